// Round 19
// baseline (4966.676 us; speedup 1.0000x reference)
//
#include <hip/hip_runtime.h>
#include <stdint.h>

typedef unsigned short u16;
typedef __attribute__((ext_vector_type(8))) short short8;
typedef __attribute__((ext_vector_type(4))) float f32x4;

#define NE   8
#define DIN  2048
#define DOUT 8192
#define NTOK 16384

__device__ __forceinline__ u16 f2bf(float f) {
  uint32_t u = __builtin_bit_cast(uint32_t, f);
  u += 0x7FFFu + ((u >> 16) & 1u);   // RNE (inputs are finite normals)
  return (u16)(u >> 16);
}

// one launch converts both X and W (two grid-stride passes)
__global__ __launch_bounds__(256) void cvt_both(
    const float* __restrict__ xs, u16* __restrict__ xd, size_t nx,
    const float* __restrict__ ws, u16* __restrict__ wd, size_t nw) {
  const size_t stride = (size_t)gridDim.x * 256 * 8;
  for (size_t i = ((size_t)blockIdx.x * 256 + threadIdx.x) * 8; i < nx; i += stride) {
    f32x4 a = __builtin_nontemporal_load((const f32x4*)(xs + i));
    f32x4 b = __builtin_nontemporal_load((const f32x4*)(xs + i + 4));
    short8 o;
    o[0] = (short)f2bf(a[0]); o[1] = (short)f2bf(a[1]);
    o[2] = (short)f2bf(a[2]); o[3] = (short)f2bf(a[3]);
    o[4] = (short)f2bf(b[0]); o[5] = (short)f2bf(b[1]);
    o[6] = (short)f2bf(b[2]); o[7] = (short)f2bf(b[3]);
    *(short8*)(xd + i) = o;
  }
  for (size_t i = ((size_t)blockIdx.x * 256 + threadIdx.x) * 8; i < nw; i += stride) {
    f32x4 a = __builtin_nontemporal_load((const f32x4*)(ws + i));
    f32x4 b = __builtin_nontemporal_load((const f32x4*)(ws + i + 4));
    short8 o;
    o[0] = (short)f2bf(a[0]); o[1] = (short)f2bf(a[1]);
    o[2] = (short)f2bf(a[2]); o[3] = (short)f2bf(a[3]);
    o[4] = (short)f2bf(b[0]); o[5] = (short)f2bf(b[1]);
    o[6] = (short)f2bf(b[2]); o[7] = (short)f2bf(b[3]);
    *(short8*)(wd + i) = o;
  }
}

#define GLOAD_LDS16(g, l) __builtin_amdgcn_global_load_lds( \
    (const __attribute__((address_space(1))) void*)(g),     \
    (__attribute__((address_space(3))) void*)(l), 16, 0, 0)

// ---------------------------------------------------------------------------
// r19: TLP without r15's confound. Tile stays 256x256 (FETCH pattern
// unchanged), but LDS double-buffer depth halves to BK=32 slices:
// 2buf x [256][32] x {A,B} = 64KB -> TWO independent blocks/CU (16 waves,
// 4/SIMD; VGPR=128 = exactly the 4-wave boundary per m69). One block's
// barrier-convergence / prologue / epilogue stalls are filled by the other
// block (the mechanism r15 tested but confounded with a tile shrink).
// Schedule per K-tile (2 barriers — same rate as r17's 4 per 64-K):
//   ph1: STAGE(nxt, t+1) [4 gloads; nxt freed at t-1 ph2's LGKM0+BAR];
//        RA4(cur,m0-3)+RB4(cur) [8 reads]; BAR; MMQ(0)
//   ph2: RA4(cur,m4-7) [4 reads]; VMW(0) [drains t+1's 4 loads — exact
//        full drain each tile => NO counted-wait tail hazards (r2)];
//        LGKM0 [all reads of cur serviced]; BAR; MMQ(4)
// Fragment addressing/swizzle byte-identical to the measured-0-conflict
// r3 pattern. Epilogue: r11's coalesced nt repack, 34.8KB single-buffered
// per-wave scratch with WAR LGKM0 (r15-verified).
// ---------------------------------------------------------------------------
__global__ __launch_bounds__(512, 4) void moe_gemm8(
    const u16* __restrict__ Xb, const u16* __restrict__ Wb,
    const int* __restrict__ counts, const float* __restrict__ bias,
    float* __restrict__ C) {
  extern __shared__ u16 sm[];  // 32768 u16 = 64 KiB

  const int tid = threadIdx.x;
  const int l = tid & 63;
  const int wid = tid >> 6;      // 0..7
  const int wr = wid >> 2;       // 0..1  (M halves of 128)
  const int wc = wid & 3;        // 0..3  (N quarters of 64)

  // XCD-bijective swizzle: 2048 blocks, 256/XCD == tiles/expert => expert==XCD
  const int id = blockIdx.x;
  const int swz = (id & 7) * 256 + (id >> 3);
  const int e = swz >> 8;
  const int rem = swz & 255;
  const int tn = rem >> 3;       // 0..31 (8 consecutive blocks share B-panel)
  const int tm = rem & 7;        // 0..7

  int off = 0;
  for (int i = 0; i < e; ++i) off += counts[i];
  const int row0 = off + tm * 256;
  const int col0 = tn * 256;
  const size_t wbase = (size_t)e * DOUT * DIN + (size_t)col0 * DIN;

  // -- staging per-lane constants (pre-swizzled global source, linear dest)
  const int rl = l >> 2;                     // row within 16-row slice
  const int q = (l & 3) ^ ((l >> 3) & 3);    // source k-granule (inverse swz)
  const int s0 = wid * 2, s1 = s0 + 1;       // this wave's 2 slices of 16
  const u16* pA0 = Xb + (size_t)(row0 + s0 * 16 + rl) * DIN + q * 8;
  const u16* pA1 = Xb + (size_t)(row0 + s1 * 16 + rl) * DIN + q * 8;
  const u16* pB0 = Wb + wbase + (size_t)(s0 * 16 + rl) * DIN + q * 8;
  const u16* pB1 = Wb + wbase + (size_t)(s1 * 16 + rl) * DIN + q * 8;

  // -- fragment-read per-lane constants (16x16 layout, r3-verified swizzle)
  const int f0 = ((l & 15) >> 1) & 3;
  const int gph = (l >> 4) ^ f0;             // physical granule 0..3
  const int aoff = (wr * 128 + (l & 15)) * 32 + gph * 8;
  const int boff = (wc * 64 + (l & 15)) * 32 + gph * 8;

  f32x4 acc[8][4] = {};
  short8 a[4], b[4];

#define SMA(buf) (sm + (buf) * 8192)             // A bf16 [2][256][32]
#define SMB(buf) (sm + 16384 + (buf) * 8192)     // B bf16 [2][256][32]
#define STAGE(buf, kt) do { const int ko = (kt) * 32;      \
    GLOAD_LDS16(pA0 + ko, SMA(buf) + s0 * 512);            \
    GLOAD_LDS16(pA1 + ko, SMA(buf) + s1 * 512);            \
    GLOAD_LDS16(pB0 + ko, SMB(buf) + s0 * 512);            \
    GLOAD_LDS16(pB1 + ko, SMB(buf) + s1 * 512); } while (0)
#define RA4(buf, mb) do { _Pragma("unroll") for (int mf = 0; mf < 4; ++mf) \
    a[mf] = *(const short8*)(SMA(buf) + aoff + ((mb) + mf) * 512); } while (0)
#define RB4(buf) do { _Pragma("unroll") for (int nf = 0; nf < 4; ++nf) \
    b[nf] = *(const short8*)(SMB(buf) + boff + nf * 512); } while (0)
#define FENCE() asm volatile("" ::: "memory")
#define BAR() do { FENCE(); __builtin_amdgcn_s_barrier(); FENCE(); } while (0)
#define VMW(N) asm volatile("s_waitcnt vmcnt(" #N ")" ::: "memory")
#define LGKM0() asm volatile("s_waitcnt lgkmcnt(0)" ::: "memory")
#define MMQ(mb) do { __builtin_amdgcn_s_setprio(1);                                \
    _Pragma("unroll") for (int mf = 0; mf < 4; ++mf)                               \
      _Pragma("unroll") for (int nf = 0; nf < 4; ++nf)                             \
        acc[(mb) + mf][nf] =                                                       \
          __builtin_amdgcn_mfma_f32_16x16x32_bf16(a[mf], b[nf], acc[(mb) + mf][nf], 0, 0, 0); \
    __builtin_amdgcn_s_setprio(0); } while (0)

  const int NKT = DIN / 32;  // 64 K-tiles

  // prologue: stage t0 only; exact drain; publish. Loop stages t+1 in ph1.
  STAGE(0, 0);
  VMW(0);
  BAR();

  for (int kt = 0; kt < NKT; kt += 2) {
#define TILE(cur, nxt, t) do {                                          \
    const bool h1 = (t) + 1 < NKT;                                      \
    /* ph1: stage t+1 first (nxt freed at t-1 ph2 LGKM0+BAR); 8 reads */\
    if (h1) STAGE(nxt, (t) + 1);                                        \
    RA4(cur, 0); RB4(cur);                                              \
    BAR(); MMQ(0);                                                      \
    /* ph2: 4 reads; exact VMW(0) drain of t+1; reads-done; publish */  \
    RA4(cur, 4);                                                        \
    if (h1) VMW(0);                                                     \
    LGKM0(); BAR(); MMQ(4); } while (0)
    TILE(0, 1, kt);
    TILE(1, 0, kt + 1);
#undef TILE
  }

  // ---- epilogue: LDS repack -> coalesced nontemporal dwordx4 stores ----
  BAR();  // all K-loop LDS reads complete; LDS is now free scratch
  float* smf = (float*)sm;
  const int cbw = col0 + wc * 64;             // wave's 64-col span
  const int r0 = (l >> 4) << 2;               // acc row offset within frag
  const f32x4 bv4 = *(const f32x4*)(bias + (size_t)e * DOUT + cbw + (l & 15) * 4);
  float* eb = smf + wid * 1088;               // 16x68 f32 per wave (34.8KB tot)

#pragma unroll
  for (int m = 0; m < 8; ++m) {
    if (m) LGKM0();   // WAR: prior readback of eb complete before overwrite
#pragma unroll
    for (int n = 0; n < 4; ++n) {
      const int c = n * 16 + (l & 15);
#pragma unroll
      for (int j = 0; j < 4; ++j)
        eb[(r0 + j) * 68 + c] = acc[m][n][j];
    }
    LGKM0();  // own writes visible (wave-private region)
    const int rbm = row0 + wr * 128 + m * 16;
#pragma unroll
    for (int i = 0; i < 4; ++i) {
      const int row = i * 4 + (l >> 4);
      f32x4 v = *(const f32x4*)(eb + row * 68 + (l & 15) * 4);
      v = v + bv4;
      __builtin_nontemporal_store(
          v, (f32x4*)(C + (size_t)(rbm + row) * DOUT + cbw + (l & 15) * 4));
    }
  }
}

// ---------------------------------------------------------------------------
// Fallback (ws too small): fused fp32->bf16 staging, 128x128 m97 structure.
// ---------------------------------------------------------------------------
__global__ __launch_bounds__(256) void moe_gemm_fused(
    const float* __restrict__ Xf, const float* __restrict__ Wf,
    const int* __restrict__ counts, const float* __restrict__ bias,
    float* __restrict__ C) {
  __shared__ __align__(16) u16 lds[2][2][128 * 32];

  const int tid = threadIdx.x;
  const int lane = tid & 63;
  const int wid = tid >> 6;
  const int wr = wid >> 1;
  const int wc = wid & 1;

  const int id = blockIdx.x;
  const int swz = (id & 7) * ((int)gridDim.x >> 3) + (id >> 3);
  const int e = swz >> 10;
  const int rem = swz & 1023;
  const int tn = rem >> 4;
  const int tml = rem & 15;

  int off = 0;
  for (int i = 0; i < e; ++i) off += counts[i];
  const int row0 = off + tml * 128;
  const int col0 = tn * 128;
  const size_t wbase = (size_t)e * DOUT * DIN + (size_t)col0 * DIN;

  f32x4 acc[4][4] = {};

  auto stage = [&](int buf, int kt) {
#pragma unroll
    for (int s = 0; s < 2; ++s) {
      int i = s * 256 + tid;
      int r = i >> 2, c = i & 3;
      const float* sa = Xf + (size_t)(row0 + r) * DIN + kt * 32 + c * 8;
      const float* sb = Wf + wbase + (size_t)r * DIN + kt * 32 + c * 8;
      f32x4 a0 = *(const f32x4*)sa;
      f32x4 a1 = *(const f32x4*)(sa + 4);
      f32x4 b0 = *(const f32x4*)sb;
      f32x4 b1 = *(const f32x4*)(sb + 4);
      short8 va, vb;
#pragma unroll
      for (int j = 0; j < 4; ++j) {
        va[j] = (short)f2bf(a0[j]); va[j + 4] = (short)f2bf(a1[j]);
        vb[j] = (short)f2bf(b0[j]); vb[j + 4] = (short)f2bf(b1[j]);
      }
      *(short8*)&lds[buf][0][i * 8] = va;
      *(short8*)&lds[buf][1][i * 8] = vb;
    }
  };

  auto compute = [&](int buf) {
    const int kc = lane >> 4;
    const int rr = lane & 15;
    short8 a[4], b[4];
    const u16* lA = lds[buf][0];
    const u16* lB = lds[buf][1];
#pragma unroll
    for (int m = 0; m < 4; ++m)
      a[m] = *(const short8*)(lA + (wr * 64 + m * 16 + rr) * 32 + kc * 8);
#pragma unroll
    for (int n = 0; n < 4; ++n)
      b[n] = *(const short8*)(lB + (wc * 64 + n * 16 + rr) * 32 + kc * 8);
#pragma unroll
    for (int m = 0; m < 4; ++m)
#pragma unroll
      for (int n = 0; n < 4; ++n)
        acc[m][n] = __builtin_amdgcn_mfma_f32_16x16x32_bf16(a[m], b[n], acc[m][n], 0, 0, 0);
  };

  stage(0, 0);
  for (int kt = 0; kt < DIN / 32; ++kt) {
    __syncthreads();
    if (kt + 1 < DIN / 32) stage((kt + 1) & 1, kt + 1);
    compute(kt & 1);
  }

  const int rbase = row0 + wr * 64;
  const int cbase = col0 + wc * 64;
#pragma unroll
  for (int n = 0; n < 4; ++n) {
    const int col = cbase + n * 16 + (lane & 15);
    const float bv = bias[e * DOUT + col];
#pragma unroll
    for (int m = 0; m < 4; ++m) {
      const int r0 = rbase + m * 16 + (lane >> 4) * 4;
#pragma unroll
      for (int j = 0; j < 4; ++j)
        C[(size_t)(r0 + j) * DOUT + col] = acc[m][n][j] + bv;
    }
  }
}

extern "C" void kernel_launch(void* const* d_in, const int* in_sizes, int n_in,
                              void* d_out, int out_size, void* d_ws, size_t ws_size,
                              hipStream_t stream) {
  const float* inp = (const float*)d_in[0];
  const int* counts = (const int*)d_in[1];
  const float* weight = (const float*)d_in[2];
  const float* bias = (const float*)d_in[3];
  float* out = (float*)d_out;

  const size_t nx = (size_t)NTOK * DIN;
  const size_t nw = (size_t)NE * DOUT * DIN;
  const size_t need = (nx + nw) * sizeof(u16);

  if (ws_size >= need) {
    u16* xb = (u16*)d_ws;
    u16* wb = xb + nx;
    cvt_both<<<4096, 256, 0, stream>>>(inp, xb, nx, weight, wb, nw);
    const int grid = (NTOK / 256) * (DOUT / 256);  // 2048
    moe_gemm8<<<grid, 512, 65536, stream>>>(xb, wb, counts, bias, out);
  } else {
    const int grid = (NTOK / 128) * (DOUT / 128);  // 8192
    moe_gemm_fused<<<grid, 256, 0, stream>>>(inp, weight, counts, bias, out);
  }
}

// Round 20
// 703.897 us; speedup vs baseline: 7.0560x; 7.0560x over previous
//
#include <hip/hip_runtime.h>
#include <stdint.h>

typedef unsigned short u16;
typedef __attribute__((ext_vector_type(8))) short short8;
typedef __attribute__((ext_vector_type(4))) float f32x4;

#define NE   8
#define DIN  2048
#define DOUT 8192
#define NTOK 16384

__device__ __forceinline__ u16 f2bf(float f) {
  uint32_t u = __builtin_bit_cast(uint32_t, f);
  u += 0x7FFFu + ((u >> 16) & 1u);   // RNE (inputs are finite normals)
  return (u16)(u >> 16);
}

__global__ __launch_bounds__(256) void cvt_f32_bf16(const float* __restrict__ src,
                                                    u16* __restrict__ dst, size_t n) {
  size_t i = ((size_t)blockIdx.x * 256 + threadIdx.x) * 8;
  const size_t stride = (size_t)gridDim.x * 256 * 8;
  for (; i < n; i += stride) {
    // nontemporal: f32 source is never re-read — keep it out of L2/L3
    f32x4 a = __builtin_nontemporal_load((const f32x4*)(src + i));
    f32x4 b = __builtin_nontemporal_load((const f32x4*)(src + i + 4));
    short8 o;
    o[0] = (short)f2bf(a[0]); o[1] = (short)f2bf(a[1]);
    o[2] = (short)f2bf(a[2]); o[3] = (short)f2bf(a[3]);
    o[4] = (short)f2bf(b[0]); o[5] = (short)f2bf(b[1]);
    o[6] = (short)f2bf(b[2]); o[7] = (short)f2bf(b[3]);
    *(short8*)(dst + i) = o;
  }
}

#define GLOAD_LDS16(g, l) __builtin_amdgcn_global_load_lds( \
    (const __attribute__((address_space(1))) void*)(g),     \
    (__attribute__((address_space(3))) void*)(l), 16, 0, 0)

// ---------------------------------------------------------------------------
// FINAL (r20) = r18 restored verbatim — verified best of the session:
// total 703.5us (GEMM ~575us = 956 TF = 38% dense peak; cvt ~125us at HBM
// roofline; coalesced nt epilogue). 19-round ledger closed every lever:
//  - K-loop schedule: r8's 4-phase/2-barrier balanced-quadrant is a
//    7-probe-verified local optimum (r4/r5/r6/r7/r9/r10/r14 all <= null).
//  - MFMA shape: 32x32x16 has an intrinsic 8-way LDS read conflict (r5,r13).
//  - W-cvt fusion: pre-pass strictly cheaper (r9 spills, r12/r16 conflicts).
//  - TLP/occupancy: 2 blocks/CU needs <=128 reg/wave incl. the 128-reg acc
//    -> spills (r19, 14.9GB scratch); tile shrink -> +85% FETCH (r15).
//  - Barriers: 2/K-tile (non-publish barriers removed, sched_barrier-pinned);
//    fewer re-bunches reads (r10).
// vmcnt discipline: counted VMW(4) drains 2-3-phase-old loads; last tile
// VMW(0) (r2: a counted wait that would no-op races the fresh stages).
// ---------------------------------------------------------------------------
__global__ __launch_bounds__(512, 2) void moe_gemm8(
    const u16* __restrict__ Xb, const u16* __restrict__ Wb,
    const int* __restrict__ counts, const float* __restrict__ bias,
    float* __restrict__ C) {
  extern __shared__ u16 sm[];  // 65536 u16 = 128 KiB

  const int tid = threadIdx.x;
  const int l = tid & 63;
  const int wid = tid >> 6;      // 0..7
  const int wr = wid >> 2;       // 0..1  (M halves of 128)
  const int wc = wid & 3;        // 0..3  (N quarters of 64)

  // XCD-bijective swizzle: 2048 blocks, 256/XCD == tiles/expert => expert==XCD
  const int id = blockIdx.x;
  const int swz = (id & 7) * 256 + (id >> 3);
  const int e = swz >> 8;
  const int rem = swz & 255;
  const int tn = rem >> 3;       // 0..31 (8 consecutive blocks share B-panel)
  const int tm = rem & 7;        // 0..7

  int off = 0;
  for (int i = 0; i < e; ++i) off += counts[i];
  const int row0 = off + tm * 256;
  const int col0 = tn * 256;
  const size_t wbase = (size_t)e * DOUT * DIN + (size_t)col0 * DIN;

  // -- staging per-lane constants (pre-swizzled global source, linear dest)
  const int rl = l >> 2;                     // row within 16-row slice
  const int q = (l & 3) ^ ((l >> 3) & 3);    // source k-granule (inverse swz)
  const int s0 = wid * 2, s1 = s0 + 1;       // this wave's 2 slices of 16
  const u16* pA0 = Xb + (size_t)(row0 + s0 * 16 + rl) * DIN + q * 8;
  const u16* pA1 = Xb + (size_t)(row0 + s1 * 16 + rl) * DIN + q * 8;
  const u16* pB0 = Wb + wbase + (size_t)(s0 * 16 + rl) * DIN + q * 8;
  const u16* pB1 = Wb + wbase + (size_t)(s1 * 16 + rl) * DIN + q * 8;

  // -- fragment-read per-lane constants (16x16 layout, r3-verified swizzle)
  const int f0 = ((l & 15) >> 1) & 3;
  const int gph = (l >> 4) ^ f0;             // physical granule 0..3
  const int aoff = (wr * 128 + (l & 15)) * 32 + gph * 8;
  const int boff = (wc * 64 + (l & 15)) * 32 + gph * 8;

  f32x4 acc[8][4] = {};
  short8 a[4], b[4];

#define SMA(buf, kh) (sm + (buf) * 32768 + (kh) * 8192)
#define SMB(buf, kh) (sm + (buf) * 32768 + 16384 + (kh) * 8192)
#define STAGE_A(buf, kt, kh) do { const int ko = (kt) * 64 + (kh) * 32; \
    GLOAD_LDS16(pA0 + ko, SMA(buf, kh) + s0 * 512);                     \
    GLOAD_LDS16(pA1 + ko, SMA(buf, kh) + s1 * 512); } while (0)
#define STAGE_B(buf, kt, kh) do { const int ko = (kt) * 64 + (kh) * 32; \
    GLOAD_LDS16(pB0 + ko, SMB(buf, kh) + s0 * 512);                     \
    GLOAD_LDS16(pB1 + ko, SMB(buf, kh) + s1 * 512); } while (0)
#define RA4(buf, kh, mb) do { _Pragma("unroll") for (int mf = 0; mf < 4; ++mf) \
    a[mf] = *(const short8*)(SMA(buf, kh) + aoff + ((mb) + mf) * 512); } while (0)
#define RB4(buf, kh) do { _Pragma("unroll") for (int nf = 0; nf < 4; ++nf) \
    b[nf] = *(const short8*)(SMB(buf, kh) + boff + nf * 512); } while (0)
#define FENCE() asm volatile("" ::: "memory")
#define BAR() do { FENCE(); __builtin_amdgcn_s_barrier(); FENCE(); } while (0)
#define SCHED0() __builtin_amdgcn_sched_barrier(0)
#define VMW(N) asm volatile("s_waitcnt vmcnt(" #N ")" ::: "memory")
#define LGKM0() asm volatile("s_waitcnt lgkmcnt(0)" ::: "memory")
#define MMQ(mb) do { __builtin_amdgcn_s_setprio(1);                                \
    _Pragma("unroll") for (int mf = 0; mf < 4; ++mf)                               \
      _Pragma("unroll") for (int nf = 0; nf < 4; ++nf)                             \
        acc[(mb) + mf][nf] =                                                       \
          __builtin_amdgcn_mfma_f32_16x16x32_bf16(a[mf], b[nf], acc[(mb) + mf][nf], 0, 0, 0); \
    __builtin_amdgcn_s_setprio(0); } while (0)

  const int NKT = DIN / 64;  // 32 K-tiles

  // prologue: tile 0 staged (kh0 first); VMW(4) publishes kh0, kh1 in flight.
  STAGE_A(0, 0, 0); STAGE_B(0, 0, 0); STAGE_A(0, 0, 1); STAGE_B(0, 0, 1);
  VMW(4);
  BAR();

  for (int kt = 0; kt < NKT; kt += 2) {
#define TILE(cur, nxt, t) do {                                          \
    const bool hn = (t) + 1 < NKT;                                      \
    /* ph1: kh0 m0-3 (12 reads; kh0 published at prior ph4-BAR) */      \
    RA4(cur, 0, 0); RB4(cur, 0);                                        \
    if (hn) STAGE_A(nxt, (t) + 1, 0);                                   \
    MMQ(0); SCHED0();   /* no hw barrier: nothing to publish */         \
    /* ph2: kh0 m4-7 ; VMW+BAR publishes cur-kh1 */                     \
    RA4(cur, 0, 4);                                                     \
    if (hn) { STAGE_B(nxt, (t) + 1, 0); VMW(4); } else VMW(0);          \
    BAR(); MMQ(4);                                                      \
    /* ph3: kh1 m0-3 (published at ph2-BAR) */                          \
    RA4(cur, 1, 0); RB4(cur, 1);                                        \
    if (hn) STAGE_A(nxt, (t) + 1, 1);                                   \
    MMQ(0); SCHED0();   /* no hw barrier: nothing to publish */         \
    /* ph4: kh1 m4-7 ; VMW+BAR publishes next-kh0 */                    \
    RA4(cur, 1, 4);                                                     \
    if (hn) { STAGE_B(nxt, (t) + 1, 1); VMW(4); }                       \
    BAR(); MMQ(4); } while (0)
    TILE(0, 1, kt);
    TILE(1, 0, kt + 1);
#undef TILE
  }

  // ---- epilogue: LDS repack -> coalesced nontemporal dwordx4 stores ----
  BAR();  // all K-loop LDS reads complete; LDS is now free scratch
  float* smf = (float*)sm;
  const int cbw = col0 + wc * 64;             // wave's 64-col span
  const int r0 = (l >> 4) << 2;               // acc row offset within frag
  const f32x4 bv4 = *(const f32x4*)(bias + (size_t)e * DOUT + cbw + (l & 15) * 4);

#pragma unroll
  for (int m = 0; m < 8; ++m) {
    float* eb = smf + (wid * 2 + (m & 1)) * 1088;   // 16x68 f32, dbuf'd
#pragma unroll
    for (int n = 0; n < 4; ++n) {
      const int c = n * 16 + (l & 15);
#pragma unroll
      for (int j = 0; j < 4; ++j)
        eb[(r0 + j) * 68 + c] = acc[m][n][j];
    }
    LGKM0();  // own writes visible (wave-private region)
    const int rbm = row0 + wr * 128 + m * 16;
#pragma unroll
    for (int i = 0; i < 4; ++i) {
      const int row = i * 4 + (l >> 4);
      f32x4 v = *(const f32x4*)(eb + row * 68 + (l & 15) * 4);
      v = v + bv4;
      __builtin_nontemporal_store(
          v, (f32x4*)(C + (size_t)(rbm + row) * DOUT + cbw + (l & 15) * 4));
    }
  }
}

// ---------------------------------------------------------------------------
// Fallback (ws too small): fused fp32->bf16 staging, 128x128 m97 structure.
// ---------------------------------------------------------------------------
__global__ __launch_bounds__(256) void moe_gemm_fused(
    const float* __restrict__ Xf, const float* __restrict__ Wf,
    const int* __restrict__ counts, const float* __restrict__ bias,
    float* __restrict__ C) {
  __shared__ __align__(16) u16 lds[2][2][128 * 32];

  const int tid = threadIdx.x;
  const int lane = tid & 63;
  const int wid = tid >> 6;
  const int wr = wid >> 1;
  const int wc = wid & 1;

  const int id = blockIdx.x;
  const int swz = (id & 7) * ((int)gridDim.x >> 3) + (id >> 3);
  const int e = swz >> 10;
  const int rem = swz & 1023;
  const int tn = rem >> 4;
  const int tml = rem & 15;

  int off = 0;
  for (int i = 0; i < e; ++i) off += counts[i];
  const int row0 = off + tml * 128;
  const int col0 = tn * 128;
  const size_t wbase = (size_t)e * DOUT * DIN + (size_t)col0 * DIN;

  f32x4 acc[4][4] = {};

  auto stage = [&](int buf, int kt) {
#pragma unroll
    for (int s = 0; s < 2; ++s) {
      int i = s * 256 + tid;
      int r = i >> 2, c = i & 3;
      const float* sa = Xf + (size_t)(row0 + r) * DIN + kt * 32 + c * 8;
      const float* sb = Wf + wbase + (size_t)r * DIN + kt * 32 + c * 8;
      f32x4 a0 = *(const f32x4*)sa;
      f32x4 a1 = *(const f32x4*)(sa + 4);
      f32x4 b0 = *(const f32x4*)sb;
      f32x4 b1 = *(const f32x4*)(sb + 4);
      short8 va, vb;
#pragma unroll
      for (int j = 0; j < 4; ++j) {
        va[j] = (short)f2bf(a0[j]); va[j + 4] = (short)f2bf(a1[j]);
        vb[j] = (short)f2bf(b0[j]); vb[j + 4] = (short)f2bf(b1[j]);
      }
      *(short8*)&lds[buf][0][i * 8] = va;
      *(short8*)&lds[buf][1][i * 8] = vb;
    }
  };

  auto compute = [&](int buf) {
    const int kc = lane >> 4;
    const int rr = lane & 15;
    short8 a[4], b[4];
    const u16* lA = lds[buf][0];
    const u16* lB = lds[buf][1];
#pragma unroll
    for (int m = 0; m < 4; ++m)
      a[m] = *(const short8*)(lA + (wr * 64 + m * 16 + rr) * 32 + kc * 8);
#pragma unroll
    for (int n = 0; n < 4; ++n)
      b[n] = *(const short8*)(lB + (wc * 64 + n * 16 + rr) * 32 + kc * 8);
#pragma unroll
    for (int m = 0; m < 4; ++m)
#pragma unroll
      for (int n = 0; n < 4; ++n)
        acc[m][n] = __builtin_amdgcn_mfma_f32_16x16x32_bf16(a[m], b[n], acc[m][n], 0, 0, 0);
  };

  stage(0, 0);
  for (int kt = 0; kt < DIN / 32; ++kt) {
    __syncthreads();
    if (kt + 1 < DIN / 32) stage((kt + 1) & 1, kt + 1);
    compute(kt & 1);
  }

  const int rbase = row0 + wr * 64;
  const int cbase = col0 + wc * 64;
#pragma unroll
  for (int n = 0; n < 4; ++n) {
    const int col = cbase + n * 16 + (lane & 15);
    const float bv = bias[e * DOUT + col];
#pragma unroll
    for (int m = 0; m < 4; ++m) {
      const int r0 = rbase + m * 16 + (lane >> 4) * 4;
#pragma unroll
      for (int j = 0; j < 4; ++j)
        C[(size_t)(r0 + j) * DOUT + col] = acc[m][n][j] + bv;
    }
  }
}

extern "C" void kernel_launch(void* const* d_in, const int* in_sizes, int n_in,
                              void* d_out, int out_size, void* d_ws, size_t ws_size,
                              hipStream_t stream) {
  const float* inp = (const float*)d_in[0];
  const int* counts = (const int*)d_in[1];
  const float* weight = (const float*)d_in[2];
  const float* bias = (const float*)d_in[3];
  float* out = (float*)d_out;

  const size_t nx = (size_t)NTOK * DIN;
  const size_t nw = (size_t)NE * DOUT * DIN;
  const size_t need = (nx + nw) * sizeof(u16);

  if (ws_size >= need) {
    u16* xb = (u16*)d_ws;
    u16* wb = xb + nx;
    cvt_f32_bf16<<<1024, 256, 0, stream>>>(inp, xb, nx);
    cvt_f32_bf16<<<4096, 256, 0, stream>>>(weight, wb, nw);
    const int grid = (NTOK / 256) * (DOUT / 256);  // 2048
    moe_gemm8<<<grid, 512, 131072, stream>>>(xb, wb, counts, bias, out);
  } else {
    const int grid = (NTOK / 128) * (DOUT / 128);  // 8192
    moe_gemm_fused<<<grid, 256, 0, stream>>>(inp, weight, counts, bias, out);
  }
}

// Round 21
// 700.880 us; speedup vs baseline: 7.0863x; 1.0043x over previous
//
#include <hip/hip_runtime.h>
#include <stdint.h>

typedef unsigned short u16;
typedef __attribute__((ext_vector_type(8))) short short8;
typedef __attribute__((ext_vector_type(4))) float f32x4;

#define NE   8
#define DIN  2048
#define DOUT 8192
#define NTOK 16384

__device__ __forceinline__ u16 f2bf(float f) {
  uint32_t u = __builtin_bit_cast(uint32_t, f);
  u += 0x7FFFu + ((u >> 16) & 1u);   // RNE (inputs are finite normals)
  return (u16)(u >> 16);
}

// single launch converts both X and W (two grid-stride passes); nontemporal
// loads keep the never-re-read f32 sources out of L2/L3 (r17-verified win).
__global__ __launch_bounds__(256) void cvt_both(
    const float* __restrict__ xs, u16* __restrict__ xd, size_t nx,
    const float* __restrict__ ws, u16* __restrict__ wd, size_t nw) {
  const size_t stride = (size_t)gridDim.x * 256 * 8;
  for (size_t i = ((size_t)blockIdx.x * 256 + threadIdx.x) * 8; i < nx; i += stride) {
    f32x4 a = __builtin_nontemporal_load((const f32x4*)(xs + i));
    f32x4 b = __builtin_nontemporal_load((const f32x4*)(xs + i + 4));
    short8 o;
    o[0] = (short)f2bf(a[0]); o[1] = (short)f2bf(a[1]);
    o[2] = (short)f2bf(a[2]); o[3] = (short)f2bf(a[3]);
    o[4] = (short)f2bf(b[0]); o[5] = (short)f2bf(b[1]);
    o[6] = (short)f2bf(b[2]); o[7] = (short)f2bf(b[3]);
    *(short8*)(xd + i) = o;
  }
  for (size_t i = ((size_t)blockIdx.x * 256 + threadIdx.x) * 8; i < nw; i += stride) {
    f32x4 a = __builtin_nontemporal_load((const f32x4*)(ws + i));
    f32x4 b = __builtin_nontemporal_load((const f32x4*)(ws + i + 4));
    short8 o;
    o[0] = (short)f2bf(a[0]); o[1] = (short)f2bf(a[1]);
    o[2] = (short)f2bf(a[2]); o[3] = (short)f2bf(a[3]);
    o[4] = (short)f2bf(b[0]); o[5] = (short)f2bf(b[1]);
    o[6] = (short)f2bf(b[2]); o[7] = (short)f2bf(b[3]);
    *(short8*)(wd + i) = o;
  }
}

#define GLOAD_LDS16(g, l) __builtin_amdgcn_global_load_lds( \
    (const __attribute__((address_space(1))) void*)(g),     \
    (__attribute__((address_space(3))) void*)(l), 16, 0, 0)

// ---------------------------------------------------------------------------
// FINAL GEMM = r18/r20 verbatim (verified best: ~575us = 960 TF = 38% dense
// peak; 43% MfmaUtil; 0 K-loop bank conflicts). 20-round ledger:
//  - schedule: 4-phase/2-barrier balanced-quadrant = 7-probe local optimum
//  - 32x32x16 MFMA: intrinsic 8-way LDS read conflict (r5,r13) — dead
//  - W-cvt fusion: pre-pass strictly cheaper (r9 spills, r12/r16 conflicts)
//  - TLP: blocked by 256-VGPR wall w/ 128-reg acc (r19: 14.9GB spill);
//    tile shrink trades +85% FETCH (r15)
//  - barriers: non-publish ones removed, order pinned w/ sched_barrier
// vmcnt: counted VMW(4) drains 2-3-phase-old loads; last tile VMW(0)
// (r2 rule: a counted wait that would no-op races the fresh stages).
// ---------------------------------------------------------------------------
__global__ __launch_bounds__(512, 2) void moe_gemm8(
    const u16* __restrict__ Xb, const u16* __restrict__ Wb,
    const int* __restrict__ counts, const float* __restrict__ bias,
    float* __restrict__ C) {
  extern __shared__ u16 sm[];  // 65536 u16 = 128 KiB

  const int tid = threadIdx.x;
  const int l = tid & 63;
  const int wid = tid >> 6;      // 0..7
  const int wr = wid >> 2;       // 0..1  (M halves of 128)
  const int wc = wid & 3;        // 0..3  (N quarters of 64)

  // XCD-bijective swizzle: 2048 blocks, 256/XCD == tiles/expert => expert==XCD
  const int id = blockIdx.x;
  const int swz = (id & 7) * 256 + (id >> 3);
  const int e = swz >> 8;
  const int rem = swz & 255;
  const int tn = rem >> 3;       // 0..31 (8 consecutive blocks share B-panel)
  const int tm = rem & 7;        // 0..7

  int off = 0;
  for (int i = 0; i < e; ++i) off += counts[i];
  const int row0 = off + tm * 256;
  const int col0 = tn * 256;
  const size_t wbase = (size_t)e * DOUT * DIN + (size_t)col0 * DIN;

  // -- staging per-lane constants (pre-swizzled global source, linear dest)
  const int rl = l >> 2;                     // row within 16-row slice
  const int q = (l & 3) ^ ((l >> 3) & 3);    // source k-granule (inverse swz)
  const int s0 = wid * 2, s1 = s0 + 1;       // this wave's 2 slices of 16
  const u16* pA0 = Xb + (size_t)(row0 + s0 * 16 + rl) * DIN + q * 8;
  const u16* pA1 = Xb + (size_t)(row0 + s1 * 16 + rl) * DIN + q * 8;
  const u16* pB0 = Wb + wbase + (size_t)(s0 * 16 + rl) * DIN + q * 8;
  const u16* pB1 = Wb + wbase + (size_t)(s1 * 16 + rl) * DIN + q * 8;

  // -- fragment-read per-lane constants (16x16 layout, r3-verified swizzle)
  const int f0 = ((l & 15) >> 1) & 3;
  const int gph = (l >> 4) ^ f0;             // physical granule 0..3
  const int aoff = (wr * 128 + (l & 15)) * 32 + gph * 8;
  const int boff = (wc * 64 + (l & 15)) * 32 + gph * 8;

  f32x4 acc[8][4] = {};
  short8 a[4], b[4];

#define SMA(buf, kh) (sm + (buf) * 32768 + (kh) * 8192)
#define SMB(buf, kh) (sm + (buf) * 32768 + 16384 + (kh) * 8192)
#define STAGE_A(buf, kt, kh) do { const int ko = (kt) * 64 + (kh) * 32; \
    GLOAD_LDS16(pA0 + ko, SMA(buf, kh) + s0 * 512);                     \
    GLOAD_LDS16(pA1 + ko, SMA(buf, kh) + s1 * 512); } while (0)
#define STAGE_B(buf, kt, kh) do { const int ko = (kt) * 64 + (kh) * 32; \
    GLOAD_LDS16(pB0 + ko, SMB(buf, kh) + s0 * 512);                     \
    GLOAD_LDS16(pB1 + ko, SMB(buf, kh) + s1 * 512); } while (0)
#define RA4(buf, kh, mb) do { _Pragma("unroll") for (int mf = 0; mf < 4; ++mf) \
    a[mf] = *(const short8*)(SMA(buf, kh) + aoff + ((mb) + mf) * 512); } while (0)
#define RB4(buf, kh) do { _Pragma("unroll") for (int nf = 0; nf < 4; ++nf) \
    b[nf] = *(const short8*)(SMB(buf, kh) + boff + nf * 512); } while (0)
#define FENCE() asm volatile("" ::: "memory")
#define BAR() do { FENCE(); __builtin_amdgcn_s_barrier(); FENCE(); } while (0)
#define SCHED0() __builtin_amdgcn_sched_barrier(0)
#define VMW(N) asm volatile("s_waitcnt vmcnt(" #N ")" ::: "memory")
#define LGKM0() asm volatile("s_waitcnt lgkmcnt(0)" ::: "memory")
#define MMQ(mb) do { __builtin_amdgcn_s_setprio(1);                                \
    _Pragma("unroll") for (int mf = 0; mf < 4; ++mf)                               \
      _Pragma("unroll") for (int nf = 0; nf < 4; ++nf)                             \
        acc[(mb) + mf][nf] =                                                       \
          __builtin_amdgcn_mfma_f32_16x16x32_bf16(a[mf], b[nf], acc[(mb) + mf][nf], 0, 0, 0); \
    __builtin_amdgcn_s_setprio(0); } while (0)

  const int NKT = DIN / 64;  // 32 K-tiles

  // prologue: tile 0 staged (kh0 first); VMW(4) publishes kh0, kh1 in flight.
  STAGE_A(0, 0, 0); STAGE_B(0, 0, 0); STAGE_A(0, 0, 1); STAGE_B(0, 0, 1);
  VMW(4);
  BAR();

  for (int kt = 0; kt < NKT; kt += 2) {
#define TILE(cur, nxt, t) do {                                          \
    const bool hn = (t) + 1 < NKT;                                      \
    /* ph1: kh0 m0-3 (12 reads; kh0 published at prior ph4-BAR) */      \
    RA4(cur, 0, 0); RB4(cur, 0);                                        \
    if (hn) STAGE_A(nxt, (t) + 1, 0);                                   \
    MMQ(0); SCHED0();   /* no hw barrier: nothing to publish */         \
    /* ph2: kh0 m4-7 ; VMW+BAR publishes cur-kh1 */                     \
    RA4(cur, 0, 4);                                                     \
    if (hn) { STAGE_B(nxt, (t) + 1, 0); VMW(4); } else VMW(0);          \
    BAR(); MMQ(4);                                                      \
    /* ph3: kh1 m0-3 (published at ph2-BAR) */                          \
    RA4(cur, 1, 0); RB4(cur, 1);                                        \
    if (hn) STAGE_A(nxt, (t) + 1, 1);                                   \
    MMQ(0); SCHED0();   /* no hw barrier: nothing to publish */         \
    /* ph4: kh1 m4-7 ; VMW+BAR publishes next-kh0 */                    \
    RA4(cur, 1, 4);                                                     \
    if (hn) { STAGE_B(nxt, (t) + 1, 1); VMW(4); }                       \
    BAR(); MMQ(4); } while (0)
    TILE(0, 1, kt);
    TILE(1, 0, kt + 1);
#undef TILE
  }

  // ---- epilogue: LDS repack -> coalesced nontemporal dwordx4 stores ----
  BAR();  // all K-loop LDS reads complete; LDS is now free scratch
  float* smf = (float*)sm;
  const int cbw = col0 + wc * 64;             // wave's 64-col span
  const int r0 = (l >> 4) << 2;               // acc row offset within frag
  const f32x4 bv4 = *(const f32x4*)(bias + (size_t)e * DOUT + cbw + (l & 15) * 4);

#pragma unroll
  for (int m = 0; m < 8; ++m) {
    float* eb = smf + (wid * 2 + (m & 1)) * 1088;   // 16x68 f32, dbuf'd
#pragma unroll
    for (int n = 0; n < 4; ++n) {
      const int c = n * 16 + (l & 15);
#pragma unroll
      for (int j = 0; j < 4; ++j)
        eb[(r0 + j) * 68 + c] = acc[m][n][j];
    }
    LGKM0();  // own writes visible (wave-private region)
    const int rbm = row0 + wr * 128 + m * 16;
#pragma unroll
    for (int i = 0; i < 4; ++i) {
      const int row = i * 4 + (l >> 4);
      f32x4 v = *(const f32x4*)(eb + row * 68 + (l & 15) * 4);
      v = v + bv4;
      __builtin_nontemporal_store(
          v, (f32x4*)(C + (size_t)(rbm + row) * DOUT + cbw + (l & 15) * 4));
    }
  }
}

// ---------------------------------------------------------------------------
// Fallback (ws too small): fused fp32->bf16 staging, 128x128 m97 structure.
// ---------------------------------------------------------------------------
__global__ __launch_bounds__(256) void moe_gemm_fused(
    const float* __restrict__ Xf, const float* __restrict__ Wf,
    const int* __restrict__ counts, const float* __restrict__ bias,
    float* __restrict__ C) {
  __shared__ __align__(16) u16 lds[2][2][128 * 32];

  const int tid = threadIdx.x;
  const int lane = tid & 63;
  const int wid = tid >> 6;
  const int wr = wid >> 1;
  const int wc = wid & 1;

  const int id = blockIdx.x;
  const int swz = (id & 7) * ((int)gridDim.x >> 3) + (id >> 3);
  const int e = swz >> 10;
  const int rem = swz & 1023;
  const int tn = rem >> 4;
  const int tml = rem & 15;

  int off = 0;
  for (int i = 0; i < e; ++i) off += counts[i];
  const int row0 = off + tml * 128;
  const int col0 = tn * 128;
  const size_t wbase = (size_t)e * DOUT * DIN + (size_t)col0 * DIN;

  f32x4 acc[4][4] = {};

  auto stage = [&](int buf, int kt) {
#pragma unroll
    for (int s = 0; s < 2; ++s) {
      int i = s * 256 + tid;
      int r = i >> 2, c = i & 3;
      const float* sa = Xf + (size_t)(row0 + r) * DIN + kt * 32 + c * 8;
      const float* sb = Wf + wbase + (size_t)r * DIN + kt * 32 + c * 8;
      f32x4 a0 = *(const f32x4*)sa;
      f32x4 a1 = *(const f32x4*)(sa + 4);
      f32x4 b0 = *(const f32x4*)sb;
      f32x4 b1 = *(const f32x4*)(sb + 4);
      short8 va, vb;
#pragma unroll
      for (int j = 0; j < 4; ++j) {
        va[j] = (short)f2bf(a0[j]); va[j + 4] = (short)f2bf(a1[j]);
        vb[j] = (short)f2bf(b0[j]); vb[j + 4] = (short)f2bf(b1[j]);
      }
      *(short8*)&lds[buf][0][i * 8] = va;
      *(short8*)&lds[buf][1][i * 8] = vb;
    }
  };

  auto compute = [&](int buf) {
    const int kc = lane >> 4;
    const int rr = lane & 15;
    short8 a[4], b[4];
    const u16* lA = lds[buf][0];
    const u16* lB = lds[buf][1];
#pragma unroll
    for (int m = 0; m < 4; ++m)
      a[m] = *(const short8*)(lA + (wr * 64 + m * 16 + rr) * 32 + kc * 8);
#pragma unroll
    for (int n = 0; n < 4; ++n)
      b[n] = *(const short8*)(lB + (wc * 64 + n * 16 + rr) * 32 + kc * 8);
#pragma unroll
    for (int m = 0; m < 4; ++m)
#pragma unroll
      for (int n = 0; n < 4; ++n)
        acc[m][n] = __builtin_amdgcn_mfma_f32_16x16x32_bf16(a[m], b[n], acc[m][n], 0, 0, 0);
  };

  stage(0, 0);
  for (int kt = 0; kt < DIN / 32; ++kt) {
    __syncthreads();
    if (kt + 1 < DIN / 32) stage((kt + 1) & 1, kt + 1);
    compute(kt & 1);
  }

  const int rbase = row0 + wr * 64;
  const int cbase = col0 + wc * 64;
#pragma unroll
  for (int n = 0; n < 4; ++n) {
    const int col = cbase + n * 16 + (lane & 15);
    const float bv = bias[e * DOUT + col];
#pragma unroll
    for (int m = 0; m < 4; ++m) {
      const int r0 = rbase + m * 16 + (lane >> 4) * 4;
#pragma unroll
      for (int j = 0; j < 4; ++j)
        C[(size_t)(r0 + j) * DOUT + col] = acc[m][n][j] + bv;
    }
  }
}

extern "C" void kernel_launch(void* const* d_in, const int* in_sizes, int n_in,
                              void* d_out, int out_size, void* d_ws, size_t ws_size,
                              hipStream_t stream) {
  const float* inp = (const float*)d_in[0];
  const int* counts = (const int*)d_in[1];
  const float* weight = (const float*)d_in[2];
  const float* bias = (const float*)d_in[3];
  float* out = (float*)d_out;

  const size_t nx = (size_t)NTOK * DIN;
  const size_t nw = (size_t)NE * DOUT * DIN;
  const size_t need = (nx + nw) * sizeof(u16);

  if (ws_size >= need) {
    u16* xb = (u16*)d_ws;
    u16* wb = xb + nx;
    cvt_both<<<4096, 256, 0, stream>>>(inp, xb, nx, weight, wb, nw);
    const int grid = (NTOK / 256) * (DOUT / 256);  // 2048
    moe_gemm8<<<grid, 512, 131072, stream>>>(xb, wb, counts, bias, out);
  } else {
    const int grid = (NTOK / 128) * (DOUT / 128);  // 8192
    moe_gemm_fused<<<grid, 256, 0, stream>>>(inp, weight, counts, bias, out);
  }
}